// Round 4
// baseline (62.913 us; speedup 1.0000x reference)
//
#include <hip/hip_runtime.h>
#include <hip/hip_cooperative_groups.h>

// DictPlenoxels forward, sigma-only, fused cooperative kernel.
//   Phase A (all 512 blocks): Dfine[nx][ny][nz] = dot32(grid[cell(n)], atoms_sigma[fcell(n)])
//            (64^3 = 1 MB, L2-resident) + per-ray start[b] (IEEE divs, once per ray).
//   grid.sync()
//   Phase B: per sample point, trilinear gather over Dfine, relu.
//
// fp contract OFF globally: reference (numpy f32) rounds mul and add separately;
// fma contraction flips floor(g+-0.5) / |p|<1 boundaries (R1 failure mode).

#pragma clang fp contract(off)

namespace cg = cooperative_groups;

#define NRAYS  1024
#define NS     219
#define NPTS   (NRAYS * NS)
#define STEPF  0.015625f          // VOXEL/2, exact power of two
#define NB     512
#define NT     256
#define NTH    (NB * NT)
#define NCELLS 32768
#define NFINE  (64 * 64 * 64)
#define WS_FLOATS (NFINE + NRAYS)

__device__ __forceinline__ void phaseA(
    const float* __restrict__ rays_o, const float* __restrict__ rays_d,
    const float* __restrict__ grid,   const float* __restrict__ atoms,
    float* __restrict__ Dfine, float* __restrict__ wstart, float* asig)
{
    const int t = threadIdx.x, bid = blockIdx.x;
    asig[t] = atoms[t * 13 + 12];          // [fcell][atom], fcell=((fx*2)+fy)*2+fz
    __syncthreads();

    if (t < 64) {
        // wave 0: 64 coarse cells per block -> 512*64 = 32768 cells, coalesced reads.
        const int c = bid * 64 + t;
        const float4* __restrict__ grow = reinterpret_cast<const float4*>(grid + c * 32);
        float4 gv[8];
#pragma unroll
        for (int q = 0; q < 8; ++q) gv[q] = grow[q];
        const int cx = c >> 10, cy = (c >> 5) & 31, cz = c & 31;
        const int base = cx * 8192 + cy * 128 + cz * 2;   // (2cx*64+2cy)*64+2cz
#pragma unroll
        for (int f = 0; f < 8; ++f) {
            float acc = 0.0f;
#pragma unroll
            for (int q = 0; q < 8; ++q) {
                const float4 av = *reinterpret_cast<const float4*>(&asig[f * 32 + q * 4]);
                acc += gv[q].x * av.x + gv[q].y * av.y + gv[q].z * av.z + gv[q].w * av.w;
            }
            Dfine[base + (f >> 2) * 4096 + ((f >> 1) & 1) * 64 + (f & 1)] = acc;
        }
    } else if (t < 66) {
        // 2 rays per block -> 1024 ray entry points, IEEE f32 divisions (match numpy).
        const int r = bid * 2 + (t - 64);
        const float ox = rays_o[r * 3 + 0], oy = rays_o[r * 3 + 1], oz = rays_o[r * 3 + 2];
        const float dx = rays_d[r * 3 + 0], dy = rays_d[r * 3 + 1], dz = rays_d[r * 3 + 2];
        const float sx = fminf((1.0f - ox) / dx, (-1.0f - ox) / dx);
        const float sy = fminf((1.0f - oy) / dy, (-1.0f - oy) / dy);
        const float sz = fminf((1.0f - oz) / dz, (-1.0f - oz) / dz);
        wstart[r] = fmaxf(sx, fmaxf(sy, sz));
    }
}

__device__ __forceinline__ void phaseB(
    const float* __restrict__ rays_o, const float* __restrict__ rays_d,
    const float* __restrict__ Dfine,  const float* __restrict__ wstart,
    float* __restrict__ out)
{
    for (int idx = blockIdx.x * NT + threadIdx.x; idx < NPTS; idx += NTH) {
        const int b = idx / NS;
        const int i = idx - b * NS;
        const float ox = rays_o[b * 3 + 0], oy = rays_o[b * 3 + 1], oz = rays_o[b * 3 + 2];
        const float dx = rays_d[b * 3 + 0], dy = rays_d[b * 3 + 1], dz = rays_d[b * 3 + 2];
        const float tt = wstart[b] + (float)i * STEPF;   // i*STEP exact (pow2)

        const float px = ox + tt * dx;   // mul then add, separate roundings
        const float py = oy + tt * dy;
        const float pz = oz + tt * dz;

        float sigma = 0.0f;
        if (px > -1.0f && px < 1.0f &&
            py > -1.0f && py < 1.0f &&
            pz > -1.0f && pz < 1.0f) {

            const float gx = (px + 1.0f) * 32.0f;
            const float gy = (py + 1.0f) * 32.0f;
            const float gz = (pz + 1.0f) * 32.0f;

            int   pX[2], pY[2], pZ[2];
            float wX[2], wY[2], wZ[2];
#pragma unroll
            for (int c = 0; c < 2; ++c) {
                const float off = c ? 0.5f : -0.5f;
                const float fx = fminf(fmaxf(floorf(gx + off), 0.0f), 63.0f);
                const float fy = fminf(fmaxf(floorf(gy + off), 0.0f), 63.0f);
                const float fz = fminf(fmaxf(floorf(gz + off), 0.0f), 63.0f);
                wX[c] = 1.0f - fabsf(gx - (fx + 0.5f));
                wY[c] = 1.0f - fabsf(gy - (fy + 0.5f));
                wZ[c] = 1.0f - fabsf(gz - (fz + 0.5f));
                pX[c] = (int)fx; pY[c] = (int)fy; pZ[c] = (int)fz;
            }

            float acc = 0.0f;
#pragma unroll
            for (int cx = 0; cx < 2; ++cx)
#pragma unroll
            for (int cy = 0; cy < 2; ++cy)
#pragma unroll
            for (int cz = 0; cz < 2; ++cz) {
                const float w3 = wX[cx] * wY[cy] * wZ[cz];   // ((wx*wy)*wz) = np.prod order
                acc += w3 * Dfine[pX[cx] * 4096 + pY[cy] * 64 + pZ[cz]];
            }
            sigma = fmaxf(acc, 0.0f);
        }
        out[idx] = sigma;
    }
}

__global__ __launch_bounds__(NT) void plenox_fused(
    const float* __restrict__ rays_o, const float* __restrict__ rays_d,
    const float* __restrict__ grid,   const float* __restrict__ atoms,
    float* __restrict__ Dfine, float* __restrict__ wstart, float* __restrict__ out)
{
    __shared__ float asig[256];
    phaseA(rays_o, rays_d, grid, atoms, Dfine, wstart, asig);
    cg::this_grid().sync();
    phaseB(rays_o, rays_d, Dfine, wstart, out);
}

// Split fallback (no grid sync needed across two dispatches).
__global__ __launch_bounds__(NT) void plenox_stage1(
    const float* __restrict__ rays_o, const float* __restrict__ rays_d,
    const float* __restrict__ grid,   const float* __restrict__ atoms,
    float* __restrict__ Dfine, float* __restrict__ wstart)
{
    __shared__ float asig[256];
    phaseA(rays_o, rays_d, grid, atoms, Dfine, wstart, asig);
}

__global__ __launch_bounds__(NT) void plenox_stage2(
    const float* __restrict__ rays_o, const float* __restrict__ rays_d,
    const float* __restrict__ Dfine,  const float* __restrict__ wstart,
    float* __restrict__ out)
{
    phaseB(rays_o, rays_d, Dfine, wstart, out);
}

extern "C" void kernel_launch(void* const* d_in, const int* in_sizes, int n_in,
                              void* d_out, int out_size, void* d_ws, size_t ws_size,
                              hipStream_t stream) {
    const float* rays_o = (const float*)d_in[0];
    const float* rays_d = (const float*)d_in[1];
    const float* grid   = (const float*)d_in[2];
    const float* atoms  = (const float*)d_in[3];
    float* out    = (float*)d_out;
    float* Dfine  = (float*)d_ws;
    float* wstart = Dfine + NFINE;

    void* args[] = {(void*)&rays_o, (void*)&rays_d, (void*)&grid, (void*)&atoms,
                    (void*)&Dfine, (void*)&wstart, (void*)&out};
    hipError_t e = hipLaunchCooperativeKernel((const void*)plenox_fused,
                                              dim3(NB), dim3(NT), args, 0, stream);
    if (e != hipSuccess) {
        hipLaunchKernelGGL(plenox_stage1, dim3(NB), dim3(NT), 0, stream,
                           rays_o, rays_d, grid, atoms, Dfine, wstart);
        hipLaunchKernelGGL(plenox_stage2, dim3(NB), dim3(NT), 0, stream,
                           rays_o, rays_d, Dfine, wstart, out);
    }
}

// Round 5
// 14.373 us; speedup vs baseline: 4.3771x; 4.3771x over previous
//
#include <hip/hip_runtime.h>

// DictPlenoxels forward, sigma-only, two launches (cooperative sync abandoned:
// grid.sync() measured ~35us on 512 blocks / 8 XCDs — 10x a graph launch gap).
//
//   Kernel A (264 blocks x 128 thr):
//     blocks 0..255:  Dfine[fine_voxel] = dot32(grid[coarse], asig[fcell]); 1 cell/thread.
//     blocks 256..263: wstart[ray] = IEEE ray-box entry t (once per ray, not per point).
//   Kernel B (1024 blocks x 256 thr): one ray per block, i = threadIdx.x sample index.
//     No integer div; ray data wave-uniform (SGPR); 8 scalar gathers from 1MB Dfine.
//
// fp contract OFF globally: reference (numpy f32) rounds mul and add separately;
// fma contraction flips floor(g+-0.5) / |p|<1 boundaries (R1 failure mode).

#pragma clang fp contract(off)

#define NRAYS  1024
#define NS     219
#define STEPF  0.015625f          // VOXEL/2, exact power of two
#define NCELLS 32768
#define NFINE  (64 * 64 * 64)

// ---------------- Kernel A: fold atoms sigma into fine table + ray starts ----------------
__global__ __launch_bounds__(128) void plenox_prep(
    const float* __restrict__ rays_o, const float* __restrict__ rays_d,
    const float* __restrict__ grid,   const float* __restrict__ atoms,
    float* __restrict__ Dfine, float* __restrict__ wstart)
{
    const int t = threadIdx.x, bid = blockIdx.x;

    if (bid < 256) {
        __shared__ __align__(16) float asig[256];   // [fcell][atom], fcell=((fx*2)+fy)*2+fz
        asig[t]       = atoms[t * 13 + 12];
        asig[t + 128] = atoms[(t + 128) * 13 + 12];
        __syncthreads();

        const int c = bid * 128 + t;                // 256*128 = 32768 cells
        const float4* __restrict__ grow = reinterpret_cast<const float4*>(grid + c * 32);
        float4 gv[8];
#pragma unroll
        for (int q = 0; q < 8; ++q) gv[q] = grow[q];

        const int cx = c >> 10, cy = (c >> 5) & 31, cz = c & 31;
        const int base = cx * 8192 + cy * 128 + cz * 2;   // fine index of (2cx,2cy,2cz)
#pragma unroll
        for (int f = 0; f < 8; ++f) {
            float acc = 0.0f;
#pragma unroll
            for (int q = 0; q < 8; ++q) {
                const float4 av = *reinterpret_cast<const float4*>(&asig[f * 32 + q * 4]);
                acc += gv[q].x * av.x + gv[q].y * av.y + gv[q].z * av.z + gv[q].w * av.w;
            }
            Dfine[base + (f >> 2) * 4096 + ((f >> 1) & 1) * 64 + (f & 1)] = acc;
        }
    } else {
        // 8 blocks x 128 threads = 1024 rays: IEEE f32 divisions (match numpy).
        const int r = (bid - 256) * 128 + t;
        const float ox = rays_o[r * 3 + 0], oy = rays_o[r * 3 + 1], oz = rays_o[r * 3 + 2];
        const float dx = rays_d[r * 3 + 0], dy = rays_d[r * 3 + 1], dz = rays_d[r * 3 + 2];
        const float sx = fminf((1.0f - ox) / dx, (-1.0f - ox) / dx);
        const float sy = fminf((1.0f - oy) / dy, (-1.0f - oy) / dy);
        const float sz = fminf((1.0f - oz) / dz, (-1.0f - oz) / dz);
        wstart[r] = fmaxf(sx, fmaxf(sy, sz));
    }
}

// ---------------- Kernel B: one ray per block, trilinear over Dfine ----------------
__global__ __launch_bounds__(256) void plenox_sample(
    const float* __restrict__ rays_o, const float* __restrict__ rays_d,
    const float* __restrict__ Dfine,  const float* __restrict__ wstart,
    float* __restrict__ out)
{
    const int b = blockIdx.x;           // ray — uniform: ray data lands in SGPRs
    const int i = threadIdx.x;          // sample
    if (i >= NS) return;

    const float ox = rays_o[b * 3 + 0], oy = rays_o[b * 3 + 1], oz = rays_o[b * 3 + 2];
    const float dx = rays_d[b * 3 + 0], dy = rays_d[b * 3 + 1], dz = rays_d[b * 3 + 2];
    const float tt = wstart[b] + (float)i * STEPF;   // i*STEP exact (pow2)

    const float px = ox + tt * dx;      // mul then add, separate roundings
    const float py = oy + tt * dy;
    const float pz = oz + tt * dz;

    float sigma = 0.0f;
    if (px > -1.0f && px < 1.0f &&
        py > -1.0f && py < 1.0f &&
        pz > -1.0f && pz < 1.0f) {

        const float gx = (px + 1.0f) * 32.0f;
        const float gy = (py + 1.0f) * 32.0f;
        const float gz = (pz + 1.0f) * 32.0f;

        int   pX[2], pY[2], pZ[2];
        float wX[2], wY[2], wZ[2];
#pragma unroll
        for (int c = 0; c < 2; ++c) {
            const float off = c ? 0.5f : -0.5f;
            const float fx = fminf(fmaxf(floorf(gx + off), 0.0f), 63.0f);
            const float fy = fminf(fmaxf(floorf(gy + off), 0.0f), 63.0f);
            const float fz = fminf(fmaxf(floorf(gz + off), 0.0f), 63.0f);
            wX[c] = 1.0f - fabsf(gx - (fx + 0.5f));
            wY[c] = 1.0f - fabsf(gy - (fy + 0.5f));
            wZ[c] = 1.0f - fabsf(gz - (fz + 0.5f));
            pX[c] = (int)fx; pY[c] = (int)fy; pZ[c] = (int)fz;
        }

        float acc = 0.0f;
#pragma unroll
        for (int cx = 0; cx < 2; ++cx)
#pragma unroll
        for (int cy = 0; cy < 2; ++cy)
#pragma unroll
        for (int cz = 0; cz < 2; ++cz) {
            const float w3 = wX[cx] * wY[cy] * wZ[cz];   // ((wx*wy)*wz) = np.prod order
            acc += w3 * Dfine[pX[cx] * 4096 + pY[cy] * 64 + pZ[cz]];
        }
        sigma = fmaxf(acc, 0.0f);
    }
    out[b * NS + i] = sigma;
}

extern "C" void kernel_launch(void* const* d_in, const int* in_sizes, int n_in,
                              void* d_out, int out_size, void* d_ws, size_t ws_size,
                              hipStream_t stream) {
    const float* rays_o = (const float*)d_in[0];
    const float* rays_d = (const float*)d_in[1];
    const float* grid   = (const float*)d_in[2];
    const float* atoms  = (const float*)d_in[3];
    float* out    = (float*)d_out;
    float* Dfine  = (float*)d_ws;
    float* wstart = Dfine + NFINE;

    hipLaunchKernelGGL(plenox_prep, dim3(264), dim3(128), 0, stream,
                       rays_o, rays_d, grid, atoms, Dfine, wstart);
    hipLaunchKernelGGL(plenox_sample, dim3(NRAYS), dim3(256), 0, stream,
                       rays_o, rays_d, Dfine, wstart, out);
}

// Round 6
// 14.210 us; speedup vs baseline: 4.4274x; 1.0115x over previous
//
#include <hip/hip_runtime.h>

// DictPlenoxels forward, sigma-only, two launches.
// Model from R2-R5: total = ~10us fixed graph-replay overhead + ~1.5us/node + work.
// Work is ~2-4us (VALU ~0.2us, gathers ~1us, stage1 ~1us) -> config below aims at
// the floor: exact-fit stage2 grid (876x256 = 224256 = NPTS, no tail, full lanes),
// minimal stage1 dispatch (132 blocks).
//
//   Kernel A (132 blocks x 256 thr):
//     blocks 0..127:  Dfine[fine_voxel] = dot32(grid[coarse], asig[fcell]); 1 cell/thread.
//     blocks 128..131: wstart[ray] = IEEE ray-box entry t (1024 rays).
//   Kernel B (876 blocks x 256 thr): flat idx = ray*219 + sample; no divisions
//     (magic-mul for /219), 8 scalar gathers from 1MB L2-resident Dfine.
//
// fp contract OFF globally: reference (numpy f32) rounds mul and add separately;
// fma contraction flips floor(g+-0.5) / |p|<1 boundaries (R1 failure mode).

#pragma clang fp contract(off)

#define NRAYS  1024
#define NS     219
#define NPTS   (NRAYS * NS)       // 224256 = 876 * 256 exactly
#define STEPF  0.015625f          // VOXEL/2, exact power of two
#define NFINE  (64 * 64 * 64)

// ---------------- Kernel A: fold atoms sigma into fine table + ray starts ----------------
__global__ __launch_bounds__(256) void plenox_prep(
    const float* __restrict__ rays_o, const float* __restrict__ rays_d,
    const float* __restrict__ grid,   const float* __restrict__ atoms,
    float* __restrict__ Dfine, float* __restrict__ wstart)
{
    const int t = threadIdx.x, bid = blockIdx.x;

    if (bid < 128) {
        __shared__ __align__(16) float asig[256];   // [fcell][atom], fcell=((fx*2)+fy)*2+fz
        asig[t] = atoms[t * 13 + 12];
        __syncthreads();

        const int c = bid * 256 + t;                // 128*256 = 32768 cells
        const float4* __restrict__ grow = reinterpret_cast<const float4*>(grid + c * 32);
        float4 gv[8];
#pragma unroll
        for (int q = 0; q < 8; ++q) gv[q] = grow[q];

        const int cx = c >> 10, cy = (c >> 5) & 31, cz = c & 31;
        const int base = cx * 8192 + cy * 128 + cz * 2;   // fine index of (2cx,2cy,2cz)
#pragma unroll
        for (int f = 0; f < 8; ++f) {
            float acc = 0.0f;
#pragma unroll
            for (int q = 0; q < 8; ++q) {
                const float4 av = *reinterpret_cast<const float4*>(&asig[f * 32 + q * 4]);
                acc += gv[q].x * av.x + gv[q].y * av.y + gv[q].z * av.z + gv[q].w * av.w;
            }
            Dfine[base + (f >> 2) * 4096 + ((f >> 1) & 1) * 64 + (f & 1)] = acc;
        }
    } else {
        // 4 blocks x 256 threads = 1024 rays: IEEE f32 divisions (match numpy).
        const int r = (bid - 128) * 256 + t;
        const float ox = rays_o[r * 3 + 0], oy = rays_o[r * 3 + 1], oz = rays_o[r * 3 + 2];
        const float dx = rays_d[r * 3 + 0], dy = rays_d[r * 3 + 1], dz = rays_d[r * 3 + 2];
        const float sx = fminf((1.0f - ox) / dx, (-1.0f - ox) / dx);
        const float sy = fminf((1.0f - oy) / dy, (-1.0f - oy) / dy);
        const float sz = fminf((1.0f - oz) / dz, (-1.0f - oz) / dz);
        wstart[r] = fmaxf(sx, fmaxf(sy, sz));
    }
}

// ---------------- Kernel B: flat sample index, trilinear over Dfine ----------------
__global__ __launch_bounds__(256) void plenox_sample(
    const float* __restrict__ rays_o, const float* __restrict__ rays_d,
    const float* __restrict__ Dfine,  const float* __restrict__ wstart,
    float* __restrict__ out)
{
    const int idx = blockIdx.x * 256 + threadIdx.x;   // grid sized exactly: no tail check
    const int b = idx / NS;                           // magic-mul, no HW div
    const int i = idx - b * NS;

    const float ox = rays_o[b * 3 + 0], oy = rays_o[b * 3 + 1], oz = rays_o[b * 3 + 2];
    const float dx = rays_d[b * 3 + 0], dy = rays_d[b * 3 + 1], dz = rays_d[b * 3 + 2];
    const float tt = wstart[b] + (float)i * STEPF;    // i*STEP exact (pow2)

    const float px = ox + tt * dx;      // mul then add, separate roundings
    const float py = oy + tt * dy;
    const float pz = oz + tt * dz;

    float sigma = 0.0f;
    if (px > -1.0f && px < 1.0f &&
        py > -1.0f && py < 1.0f &&
        pz > -1.0f && pz < 1.0f) {

        const float gx = (px + 1.0f) * 32.0f;
        const float gy = (py + 1.0f) * 32.0f;
        const float gz = (pz + 1.0f) * 32.0f;

        int   pX[2], pY[2], pZ[2];
        float wX[2], wY[2], wZ[2];
#pragma unroll
        for (int c = 0; c < 2; ++c) {
            const float off = c ? 0.5f : -0.5f;
            const float fx = fminf(fmaxf(floorf(gx + off), 0.0f), 63.0f);
            const float fy = fminf(fmaxf(floorf(gy + off), 0.0f), 63.0f);
            const float fz = fminf(fmaxf(floorf(gz + off), 0.0f), 63.0f);
            wX[c] = 1.0f - fabsf(gx - (fx + 0.5f));
            wY[c] = 1.0f - fabsf(gy - (fy + 0.5f));
            wZ[c] = 1.0f - fabsf(gz - (fz + 0.5f));
            pX[c] = (int)fx; pY[c] = (int)fy; pZ[c] = (int)fz;
        }

        float acc = 0.0f;
#pragma unroll
        for (int cx = 0; cx < 2; ++cx)
#pragma unroll
        for (int cy = 0; cy < 2; ++cy)
#pragma unroll
        for (int cz = 0; cz < 2; ++cz) {
            const float w3 = wX[cx] * wY[cy] * wZ[cz];   // ((wx*wy)*wz) = np.prod order
            acc += w3 * Dfine[pX[cx] * 4096 + pY[cy] * 64 + pZ[cz]];
        }
        sigma = fmaxf(acc, 0.0f);
    }
    out[idx] = sigma;
}

extern "C" void kernel_launch(void* const* d_in, const int* in_sizes, int n_in,
                              void* d_out, int out_size, void* d_ws, size_t ws_size,
                              hipStream_t stream) {
    const float* rays_o = (const float*)d_in[0];
    const float* rays_d = (const float*)d_in[1];
    const float* grid   = (const float*)d_in[2];
    const float* atoms  = (const float*)d_in[3];
    float* out    = (float*)d_out;
    float* Dfine  = (float*)d_ws;
    float* wstart = Dfine + NFINE;

    hipLaunchKernelGGL(plenox_prep, dim3(132), dim3(256), 0, stream,
                       rays_o, rays_d, grid, atoms, Dfine, wstart);
    hipLaunchKernelGGL(plenox_sample, dim3(NPTS / 256), dim3(256), 0, stream,
                       rays_o, rays_d, Dfine, wstart, out);
}